// Round 1
// baseline (54.316 us; speedup 1.0000x reference)
//
#include <hip/hip_runtime.h>

#define NB 2
#define C 32
#define H 128
#define W 256
#define D 48
// 5x5 filter, dilation 2 -> offsets {-4,-2,0,2,4}

// ---------------------------------------------------------------------------
// Kernel Z: z[n][d][h][w] = sum_c x[n][c][h][w] * y[n][c][h][w-d]  (0 if w<d)
// One block per (n,h). 256 threads, thread = w.
// y row staged in LDS (32x256 f32 = 32KB); x column held in 32 VGPRs.
// ---------------------------------------------------------------------------
__global__ __launch_bounds__(256) void zkern(const float* __restrict__ x,
                                             const float* __restrict__ y,
                                             float* __restrict__ z) {
    const int nh = blockIdx.x;           // n*H + h
    const int n  = nh / H;
    const int h  = nh % H;
    const int w  = threadIdx.x;          // 0..255

    __shared__ float ys[C][W];

    const size_t rowbase = ((size_t)(n * C) * H + h) * (size_t)W;  // x[n][0][h][0]
    const float* xrow = x + rowbase;
    const float* yrow = y + rowbase;

    float xv[C];
#pragma unroll
    for (int c = 0; c < C; ++c) {
        xv[c]    = xrow[(size_t)c * H * W + w];
        ys[c][w] = yrow[(size_t)c * H * W + w];
    }
    __syncthreads();

    float* zbase = z + (((size_t)n * D) * H + h) * (size_t)W + w;
    for (int d = 0; d < D; ++d) {
        float acc = 0.f;
        if (w >= d) {
            const int wd = w - d;
#pragma unroll
            for (int c = 0; c < C; ++c) acc += xv[c] * ys[c][wd];
        }
        zbase[(size_t)d * H * W] = acc;
    }
}

// ---------------------------------------------------------------------------
// Kernel F: out[n][d][h][w] = bias[n][h][w]
//                           + sum_{i,j} F[n][i*5+j][h][w] * z[n][d][h+2(i-2)][w+2(j-2)]
// One block per (n, h, d-chunk). 256 threads, thread = w.
// 25 filter taps + bias held in VGPRs, reused across DCHUNK disparities.
// ---------------------------------------------------------------------------
#define DCHUNKS 4
#define DCHUNK (D / DCHUNKS)   // 12

__global__ __launch_bounds__(256) void fkern(const float* __restrict__ z,
                                             const float* __restrict__ F,
                                             const float* __restrict__ B,
                                             float* __restrict__ out) {
    const int b     = blockIdx.x;        // (n*H + h)*DCHUNKS + chunk
    const int chunk = b % DCHUNKS;
    const int nh    = b / DCHUNKS;
    const int n     = nh / H;
    const int h     = nh % H;
    const int w     = threadIdx.x;

    float f[25];
#pragma unroll
    for (int t = 0; t < 25; ++t)
        f[t] = F[(((size_t)n * 25 + t) * H + h) * (size_t)W + w];
    const float bias = B[((size_t)n * H + h) * (size_t)W + w];

    const float* zb = z + (size_t)n * D * H * W;

    for (int dd = 0; dd < DCHUNK; ++dd) {
        const int d = chunk * DCHUNK + dd;
        const float* zd = zb + (size_t)d * H * W;
        float acc = bias;
#pragma unroll
        for (int i = 0; i < 5; ++i) {
            const int hh = h + 2 * i - 4;
            if (hh < 0 || hh >= H) continue;          // wave-uniform (h uniform per block)
            const float* zrow = zd + (size_t)hh * W;
#pragma unroll
            for (int j = 0; j < 5; ++j) {
                const int ww = w + 2 * j - 4;
                const float zv = (ww >= 0 && ww < W) ? zrow[ww] : 0.f;
                acc += f[i * 5 + j] * zv;
            }
        }
        out[(((size_t)n * D + d) * H + h) * (size_t)W + w] = acc;
    }
}

// ---------------------------------------------------------------------------
// Fallback (workspace too small): fully fused naive version. Correctness only.
// ---------------------------------------------------------------------------
__global__ __launch_bounds__(256) void fused_naive(const float* __restrict__ x,
                                                   const float* __restrict__ y,
                                                   const float* __restrict__ F,
                                                   const float* __restrict__ B,
                                                   float* __restrict__ out) {
    const size_t idx = (size_t)blockIdx.x * 256 + threadIdx.x;
    if (idx >= (size_t)NB * D * H * W) return;
    const int w = (int)(idx % W);
    const int h = (int)((idx / W) % H);
    const int d = (int)((idx / ((size_t)W * H)) % D);
    const int n = (int)(idx / ((size_t)W * H * D));

    float acc = B[((size_t)n * H + h) * W + w];
#pragma unroll
    for (int i = 0; i < 5; ++i) {
        const int hh = h + 2 * i - 4;
        if (hh < 0 || hh >= H) continue;
#pragma unroll
        for (int j = 0; j < 5; ++j) {
            const int ww = w + 2 * j - 4;
            if (ww < 0 || ww >= W) continue;
            const int ws_ = ww - d;                 // shifted y column
            float zv = 0.f;
            if (ws_ >= 0) {
                const float* xp = x + (((size_t)n * C) * H + hh) * (size_t)W + ww;
                const float* yp = y + (((size_t)n * C) * H + hh) * (size_t)W + ws_;
                for (int c = 0; c < C; ++c)
                    zv += xp[(size_t)c * H * W] * yp[(size_t)c * H * W];
            }
            acc += F[(((size_t)n * 25 + i * 5 + j) * H + h) * (size_t)W + w] * zv;
        }
    }
    out[idx] = acc;
}

extern "C" void kernel_launch(void* const* d_in, const int* in_sizes, int n_in,
                              void* d_out, int out_size, void* d_ws, size_t ws_size,
                              hipStream_t stream) {
    const float* x = (const float*)d_in[0];
    const float* y = (const float*)d_in[1];
    const float* F = (const float*)d_in[2];
    const float* B = (const float*)d_in[3];
    float* out = (float*)d_out;

    const size_t zbytes = (size_t)NB * D * H * W * sizeof(float);

    if (ws_size >= zbytes) {
        float* z = (float*)d_ws;
        zkern<<<NB * H, 256, 0, stream>>>(x, y, z);
        fkern<<<NB * H * DCHUNKS, 256, 0, stream>>>(z, F, B, out);
    } else {
        const size_t total = (size_t)NB * D * H * W;
        fused_naive<<<(int)((total + 255) / 256), 256, 0, stream>>>(x, y, F, B, out);
    }
}

// Round 2
// 34.558 us; speedup vs baseline: 1.5717x; 1.5717x over previous
//
#include <hip/hip_runtime.h>

#define NB 2
#define C 32
#define H 128
#define W 256
#define D 48
#define HW (H * W)

// ---------------------------------------------------------------------------
// zkern v2: z[n][d][h][w] = sum_c x[n][c][h][w] * y[n][c][h][w-d]  (0 if w<d)
// Grid NB*H (=256) blocks x 1024 threads (16 waves -> 4/SIMD).
// Thread = (dgroup 0..7, w-pair 0..127). dgroup owns 6 disparities.
// y row staged in LDS with 48-float zero left-pad (kills the w<d branch).
// 7-float sliding window per c serves 2w x 6d = 12 FMAs.
// Lane LDS stride = 2 floats -> 2-way aliasing = free.
// ---------------------------------------------------------------------------
__global__ __launch_bounds__(1024) void zkern(const float* __restrict__ x,
                                              const float* __restrict__ y,
                                              float* __restrict__ z) {
    const int nh  = blockIdx.x;
    const int n   = nh / H;
    const int h   = nh % H;
    const int tid = threadIdx.x;
    const int w2  = tid & 127;   // w-pair: covers w = 2*w2, 2*w2+1
    const int dg  = tid >> 7;    // 0..7
    const int d0  = dg * 6;

    __shared__ float ys[C][304];  // [0..47] = zero pad, [48+w] = y[c][w]

    const float* xrow = x + ((size_t)(n * C) * H + h) * (size_t)W;
    const float* yrow = y + ((size_t)(n * C) * H + h) * (size_t)W;

    // stage y (each dgroup stages 4 channels; all share the result)
#pragma unroll
    for (int cc = 0; cc < 4; ++cc) {
        const int c = dg * 4 + cc;
        const float2 v = *(const float2*)(yrow + (size_t)c * HW + 2 * w2);
        *(float2*)&ys[c][48 + 2 * w2] = v;
        if (w2 < 24) { ys[c][2 * w2] = 0.f; ys[c][2 * w2 + 1] = 0.f; }
    }
    __syncthreads();

    float acc[2][6] = {};
    const int base = 2 * w2 + 43 - d0;   // win[m] = ys[c][base+m], m=0..6

#pragma unroll 8
    for (int c = 0; c < C; ++c) {
        const float2 xv = *(const float2*)(xrow + (size_t)c * HW + 2 * w2);
        float win[7];
#pragma unroll
        for (int m = 0; m < 7; ++m) win[m] = ys[c][base + m];
        // acc[o][k] += xv[o] * ys[c][2w2+o+48-(d0+k)] ; index = base + 5+o-k
#pragma unroll
        for (int k = 0; k < 6; ++k) {
            acc[0][k] += xv.x * win[5 - k];
            acc[1][k] += xv.y * win[6 - k];
        }
    }

    float* zp = z + (((size_t)n * D + d0) * H + h) * (size_t)W + 2 * w2;
#pragma unroll
    for (int k = 0; k < 6; ++k) {
        float2 v; v.x = acc[0][k]; v.y = acc[1][k];
        *(float2*)(zp + (size_t)k * HW) = v;
    }
}

// ---------------------------------------------------------------------------
// fkern v2: out[n][d][h][w] = bias + sum_{i,j} F[n][i*5+j][h][w] *
//                                        z[n][d][h+2(i-2)][w+2(j-2)]
// Grid NB*H*6 (=1536) blocks x 256 threads. Block owns 8 disparities.
// z slab (8d x 5 rows, w-padded +-4, h-OOB rows zeroed) staged in 41 KB LDS
// via float4 -> compute is 200 branch-free conflict-free LDS reads + 200 FMA.
// ---------------------------------------------------------------------------
#define DCH 8
#define NCH (D / DCH)   // 6

__global__ __launch_bounds__(256) void fkern(const float* __restrict__ z,
                                             const float* __restrict__ F,
                                             const float* __restrict__ B,
                                             float* __restrict__ out) {
    __shared__ float zs[DCH * 5][264];   // row r = dd*5 + i ; col 0 <-> z col -4

    const int b  = blockIdx.x;
    const int ch = b % NCH;
    const int nh = b / NCH;
    const int n  = nh / H;
    const int h  = nh % H;
    const int w  = threadIdx.x;
    const int d0 = ch * DCH;

    // stage: 40 rows x 66 float4
#pragma unroll
    for (int it = 0; it < 11; ++it) {
        const int f4 = it * 256 + w;
        if (f4 < 40 * 66) {
            const int r  = f4 / 66;
            const int q  = f4 % 66;
            const int dd = r / 5;
            const int i  = r % 5;
            const int hh = h + 2 * i - 4;
            float4 v = {0.f, 0.f, 0.f, 0.f};
            if (q >= 1 && q <= 64 && hh >= 0 && hh < H) {
                v = *(const float4*)(z + (((size_t)n * D + d0 + dd) * H + hh) * (size_t)W
                                       + 4 * q - 4);
            }
            *(float4*)&zs[r][4 * q] = v;
        }
    }

    // taps + bias (issued before the sync so the loads overlap staging)
    float f[25];
#pragma unroll
    for (int t = 0; t < 25; ++t)
        f[t] = F[(((size_t)n * 25 + t) * H + h) * (size_t)W + w];
    const float bias = B[((size_t)n * H + h) * (size_t)W + w];

    __syncthreads();

    float* op = out + (((size_t)n * D + d0) * H + h) * (size_t)W + w;
#pragma unroll
    for (int dd = 0; dd < DCH; ++dd) {
        float acc = bias;
#pragma unroll
        for (int i = 0; i < 5; ++i) {
            const float* zr = &zs[dd * 5 + i][w];
#pragma unroll
            for (int j = 0; j < 5; ++j)
                acc += f[i * 5 + j] * zr[2 * j];
        }
        op[(size_t)dd * HW] = acc;
    }
}

// ---------------------------------------------------------------------------
// Fallback (workspace too small): fully fused naive version. Correctness only.
// ---------------------------------------------------------------------------
__global__ __launch_bounds__(256) void fused_naive(const float* __restrict__ x,
                                                   const float* __restrict__ y,
                                                   const float* __restrict__ F,
                                                   const float* __restrict__ B,
                                                   float* __restrict__ out) {
    const size_t idx = (size_t)blockIdx.x * 256 + threadIdx.x;
    if (idx >= (size_t)NB * D * H * W) return;
    const int w = (int)(idx % W);
    const int h = (int)((idx / W) % H);
    const int d = (int)((idx / ((size_t)W * H)) % D);
    const int n = (int)(idx / ((size_t)W * H * D));

    float acc = B[((size_t)n * H + h) * W + w];
#pragma unroll
    for (int i = 0; i < 5; ++i) {
        const int hh = h + 2 * i - 4;
        if (hh < 0 || hh >= H) continue;
#pragma unroll
        for (int j = 0; j < 5; ++j) {
            const int ww = w + 2 * j - 4;
            if (ww < 0 || ww >= W) continue;
            const int ws_ = ww - d;
            float zv = 0.f;
            if (ws_ >= 0) {
                const float* xp = x + (((size_t)n * C) * H + hh) * (size_t)W + ww;
                const float* yp = y + (((size_t)n * C) * H + hh) * (size_t)W + ws_;
                for (int c = 0; c < C; ++c)
                    zv += xp[(size_t)c * HW] * yp[(size_t)c * HW];
            }
            acc += F[(((size_t)n * 25 + i * 5 + j) * H + h) * (size_t)W + w] * zv;
        }
    }
    out[idx] = acc;
}

extern "C" void kernel_launch(void* const* d_in, const int* in_sizes, int n_in,
                              void* d_out, int out_size, void* d_ws, size_t ws_size,
                              hipStream_t stream) {
    const float* x = (const float*)d_in[0];
    const float* y = (const float*)d_in[1];
    const float* F = (const float*)d_in[2];
    const float* B = (const float*)d_in[3];
    float* out = (float*)d_out;

    const size_t zbytes = (size_t)NB * D * H * W * sizeof(float);

    if (ws_size >= zbytes) {
        float* z = (float*)d_ws;
        zkern<<<NB * H, 1024, 0, stream>>>(x, y, z);
        fkern<<<NB * H * NCH, 256, 0, stream>>>(z, F, B, out);
    } else {
        const size_t total = (size_t)NB * D * H * W;
        fused_naive<<<(int)((total + 255) / 256), 256, 0, stream>>>(x, y, F, B, out);
    }
}